// Round 4
// baseline (350.666 us; speedup 1.0000x reference)
//
#include <hip/hip_runtime.h>
#include <math.h>

namespace {

constexpr int Bb   = 128;
constexpr int Ss   = 196;
constexpr int DIN  = 512;
constexpr int Hh   = 8;
constexpr int DKc  = 32;
constexpr int DVc  = 128;
constexpr int QKVD = 1536;   // H*(2*DK+DV)
constexpr int PIN  = 1024;   // H*DV
constexpr int Mrows = Bb * Ss; // 25088
constexpr float EPSc   = 1e-3f;
constexpr float SCALEc = 0.17677669529663687f; // 32^-0.5

// VT padded layout: [1024 channels][128 b * 200 s] bf16
constexpr int VT_NP = 25600;

typedef __bf16 bf16x8 __attribute__((ext_vector_type(8)));
typedef __bf16 bf16x4 __attribute__((ext_vector_type(4)));
typedef float  f32x4  __attribute__((ext_vector_type(4)));

__device__ __forceinline__ void gl_lds16(const void* g, void* l) {
    __builtin_amdgcn_global_load_lds(
        (const __attribute__((address_space(1))) void*)g,
        (__attribute__((address_space(3))) void*)l, 16, 0, 0);
}

// ---------------- fp32 -> bf16 elementwise convert (x) ----------------
__global__ __launch_bounds__(256)
void cvt_f32_bf16(const float* __restrict__ in, __bf16* __restrict__ out, int n4)
{
    int i = blockIdx.x * 256 + threadIdx.x;
    if (i < n4) {
        float4 v = ((const float4*)in)[i];
        bf16x4 o = { (__bf16)v.x, (__bf16)v.y, (__bf16)v.z, (__bf16)v.w };
        ((bf16x4*)out)[i] = o;
    }
}

// ---------------- plain W[K][N] fp32 -> WT[N][K] bf16 (for W_proj) ----------------
__global__ __launch_bounds__(256)
void transpose_cvt(const float* __restrict__ W, __bf16* __restrict__ WT, int K, int N)
{
    __shared__ float tile[32][33];
    const int n0 = blockIdx.x * 32, k0 = blockIdx.y * 32;
    const int tx = threadIdx.x & 31, ty = threadIdx.x >> 5;
#pragma unroll
    for (int i = ty; i < 32; i += 8)
        tile[i][tx] = W[(size_t)(k0 + i) * N + n0 + tx];
    __syncthreads();
#pragma unroll
    for (int i = ty; i < 32; i += 8)
        WT[(size_t)(n0 + i) * K + k0 + tx] = (__bf16)tile[tx][i];
}

// ---- W_qkv Q/K columns -> WTqk[512][512]: row n' = h*64+c <-> col h*192+c ----
__global__ __launch_bounds__(256)
void transpose_qkmap(const float* __restrict__ W, __bf16* __restrict__ WT)
{
    __shared__ float tile[32][33];
    const int n0p = blockIdx.x * 32, k0 = blockIdx.y * 32;
    const int norig0 = (n0p >> 6) * 192 + (n0p & 63);
    const int tx = threadIdx.x & 31, ty = threadIdx.x >> 5;
#pragma unroll
    for (int i = ty; i < 32; i += 8)
        tile[i][tx] = W[(size_t)(k0 + i) * QKVD + norig0 + tx];
    __syncthreads();
#pragma unroll
    for (int i = ty; i < 32; i += 8)
        WT[(size_t)(n0p + i) * DIN + k0 + tx] = (__bf16)tile[tx][i];
}

// ---- W_qkv V columns -> WTv[1024][512]: row m' = h*128+d <-> col h*192+64+d ----
__global__ __launch_bounds__(256)
void transpose_vmap(const float* __restrict__ W, __bf16* __restrict__ WT)
{
    __shared__ float tile[32][33];
    const int n0p = blockIdx.x * 32, k0 = blockIdx.y * 32;
    const int norig0 = (n0p >> 7) * 192 + 64 + (n0p & 127);
    const int tx = threadIdx.x & 31, ty = threadIdx.x >> 5;
#pragma unroll
    for (int i = ty; i < 32; i += 8)
        tile[i][tx] = W[(size_t)(k0 + i) * QKVD + norig0 + tx];
    __syncthreads();
#pragma unroll
    for (int i = ty; i < 32; i += 8)
        WT[(size_t)(n0p + i) * DIN + k0 + tx] = (__bf16)tile[tx][i];
}

// ---------------- gemm_qk: xb @ WTqk^T + BN -> QKbuf [h][25088][64] bf16 ----------------
// Q channels (c<32) pre-scaled by SCALE (folds softmax scale).
__global__ __launch_bounds__(256)
void gemm_qk(const __bf16* __restrict__ A, const __bf16* __restrict__ BT,
             const float* __restrict__ bias, const float* __restrict__ gamma,
             const float* __restrict__ beta, const float* __restrict__ mean,
             const float* __restrict__ var, __bf16* __restrict__ QKb)
{
    constexpr int N = 512, K = DIN;
    __shared__ __bf16 As[128 * 32];
    __shared__ __bf16 Bs[128 * 32];
    const int t = threadIdx.x, wave = t >> 6, lane = t & 63;
    const int lr = lane & 15, q = lane >> 4;
    const int m0 = (int)(blockIdx.x >> 2) * 128;
    const int n0 = (int)(blockIdx.x & 3) * 128;
    const int wm = (wave & 1) * 64, wn = (wave >> 1) * 64;
    const __bf16* aG0 = A  + (size_t)(m0 + (t >> 2)) * K + (t & 3) * 8;
    const __bf16* aG1 = aG0 + (size_t)64 * K;
    const __bf16* bG0 = BT + (size_t)(n0 + (t >> 2)) * K + (t & 3) * 8;
    const __bf16* bG1 = bG0 + (size_t)64 * K;
    char* lA = (char*)As + wave * 1024;
    char* lB = (char*)Bs + wave * 1024;
    f32x4 acc[4][4] = {};
    for (int k0 = 0; k0 < K; k0 += 32) {
        gl_lds16(aG0 + k0, lA);
        gl_lds16(aG1 + k0, lA + 4096);
        gl_lds16(bG0 + k0, lB);
        gl_lds16(bG1 + k0, lB + 4096);
        __syncthreads();
        bf16x8 aF[4], bF[4];
#pragma unroll
        for (int i = 0; i < 4; ++i)
            aF[i] = *(const bf16x8*)(As + (wm + i * 16 + lr) * 32 + q * 8);
#pragma unroll
        for (int j = 0; j < 4; ++j)
            bF[j] = *(const bf16x8*)(Bs + (wn + j * 16 + lr) * 32 + q * 8);
#pragma unroll
        for (int i = 0; i < 4; ++i)
#pragma unroll
            for (int j = 0; j < 4; ++j)
                acc[i][j] = __builtin_amdgcn_mfma_f32_16x16x32_bf16(
                    aF[i], bF[j], acc[i][j], 0, 0, 0);
        __syncthreads();
    }
#pragma unroll
    for (int j = 0; j < 4; ++j) {
        const int np = n0 + wn + j * 16 + lr;       // n' = h*64+c
        const int h = np >> 6, c = np & 63;
        const int norig = h * 192 + c;
        float s  = gamma[norig] * rsqrtf(var[norig] + EPSc);
        float tv = fmaf(bias[norig] - mean[norig], s, beta[norig]);
        if (c < 32) { s *= SCALEc; tv *= SCALEc; }   // fold softmax scale into Q
        __bf16* dst = QKb + (size_t)h * (25088 * 64) + c;
#pragma unroll
        for (int i = 0; i < 4; ++i) {
            const int mrow = m0 + wm + i * 16 + q * 4;
#pragma unroll
            for (int r = 0; r < 4; ++r)
                dst[(size_t)(mrow + r) * 64] = (__bf16)fmaf(acc[i][j][r], s, tv);
        }
    }
}

// ---------------- gemm_vt: V^T = WTv @ xb^T + BN -> VT[1024][25600] bf16 ----------------
// m' = h*128+d (channel), n' = b*200+s (s padded 196->200).
__global__ __launch_bounds__(256)
void gemm_vt(const __bf16* __restrict__ A /*WTv[1024][512]*/,
             const __bf16* __restrict__ BT /*xb[25088][512]*/,
             const float* __restrict__ bias, const float* __restrict__ gamma,
             const float* __restrict__ beta, const float* __restrict__ mean,
             const float* __restrict__ var, __bf16* __restrict__ VT)
{
    constexpr int K = DIN;
    __shared__ __bf16 As[128 * 32];
    __shared__ __bf16 Bs[128 * 32];
    const int t = threadIdx.x, wave = t >> 6, lane = t & 63;
    const int lr = lane & 15, q = lane >> 4;
    const int m0 = (int)(blockIdx.x / 200) * 128;
    const int n0 = (int)(blockIdx.x % 200) * 128;
    const int wm = (wave & 1) * 64, wn = (wave >> 1) * 64;

    // BT rows are n' = b*200+s -> xb row b*196+min(s,195)
    auto xrow = [](int np) {
        int bb = np / 200, ss = np - bb * 200;
        return bb * 196 + (ss < 196 ? ss : 195);
    };
    const __bf16* aG0 = A + (size_t)(m0 + (t >> 2)) * K + (t & 3) * 8;
    const __bf16* aG1 = aG0 + (size_t)64 * K;
    const __bf16* bG0 = BT + (size_t)xrow(n0 + (t >> 2)) * K + (t & 3) * 8;
    const __bf16* bG1 = BT + (size_t)xrow(n0 + 64 + (t >> 2)) * K + (t & 3) * 8;
    char* lA = (char*)As + wave * 1024;
    char* lB = (char*)Bs + wave * 1024;
    f32x4 acc[4][4] = {};
    for (int k0 = 0; k0 < K; k0 += 32) {
        gl_lds16(aG0 + k0, lA);
        gl_lds16(aG1 + k0, lA + 4096);
        gl_lds16(bG0 + k0, lB);
        gl_lds16(bG1 + k0, lB + 4096);
        __syncthreads();
        bf16x8 aF[4], bF[4];
#pragma unroll
        for (int i = 0; i < 4; ++i)
            aF[i] = *(const bf16x8*)(As + (wm + i * 16 + lr) * 32 + q * 8);
#pragma unroll
        for (int j = 0; j < 4; ++j)
            bF[j] = *(const bf16x8*)(Bs + (wn + j * 16 + lr) * 32 + q * 8);
#pragma unroll
        for (int i = 0; i < 4; ++i)
#pragma unroll
            for (int j = 0; j < 4; ++j)
                acc[i][j] = __builtin_amdgcn_mfma_f32_16x16x32_bf16(
                    aF[i], bF[j], acc[i][j], 0, 0, 0);
        __syncthreads();
    }
    // BN params indexed by the CHANNEL = m-row here.
#pragma unroll
    for (int i = 0; i < 4; ++i) {
        const int mbase = m0 + wm + i * 16 + q * 4;
#pragma unroll
        for (int r = 0; r < 4; ++r) {
            const int m = mbase + r;                 // h*128+d
            const int norig = (m >> 7) * 192 + 64 + (m & 127);
            const float s  = gamma[norig] * rsqrtf(var[norig] + EPSc);
            const float tv = fmaf(bias[norig] - mean[norig], s, beta[norig]);
            __bf16* dst = VT + (size_t)m * VT_NP + n0 + wn;
#pragma unroll
            for (int j = 0; j < 4; ++j)
                dst[j * 16 + lr] = (__bf16)fmaf(acc[i][j][r], s, tv);
        }
    }
}

// ---------------- generic bf16 MFMA GEMM + BN (fp32 out) — GEMM2 ----------------
template<int N, int K>
__global__ __launch_bounds__(256)
void gemm_bn_mfma(const __bf16* __restrict__ A, const __bf16* __restrict__ BT,
                  const float* __restrict__ bias, const float* __restrict__ gamma,
                  const float* __restrict__ beta, const float* __restrict__ mean,
                  const float* __restrict__ var, float* __restrict__ C)
{
    __shared__ __bf16 As[128 * 32];
    __shared__ __bf16 Bs[128 * 32];
    const int t = threadIdx.x, wave = t >> 6, lane = t & 63;
    const int lr = lane & 15, q = lane >> 4;
    constexpr int ntiles = N / 128;
    const int m0 = (int)(blockIdx.x / ntiles) * 128;
    const int n0 = (int)(blockIdx.x % ntiles) * 128;
    const int wm = (wave & 1) * 64, wn = (wave >> 1) * 64;
    const __bf16* aG0 = A  + (size_t)(m0 + (t >> 2)) * K + (t & 3) * 8;
    const __bf16* aG1 = aG0 + (size_t)64 * K;
    const __bf16* bG0 = BT + (size_t)(n0 + (t >> 2)) * K + (t & 3) * 8;
    const __bf16* bG1 = bG0 + (size_t)64 * K;
    char* lA = (char*)As + wave * 1024;
    char* lB = (char*)Bs + wave * 1024;
    f32x4 acc[4][4] = {};
    for (int k0 = 0; k0 < K; k0 += 32) {
        gl_lds16(aG0 + k0, lA);
        gl_lds16(aG1 + k0, lA + 4096);
        gl_lds16(bG0 + k0, lB);
        gl_lds16(bG1 + k0, lB + 4096);
        __syncthreads();
        bf16x8 aF[4], bF[4];
#pragma unroll
        for (int i = 0; i < 4; ++i)
            aF[i] = *(const bf16x8*)(As + (wm + i * 16 + lr) * 32 + q * 8);
#pragma unroll
        for (int j = 0; j < 4; ++j)
            bF[j] = *(const bf16x8*)(Bs + (wn + j * 16 + lr) * 32 + q * 8);
#pragma unroll
        for (int i = 0; i < 4; ++i)
#pragma unroll
            for (int j = 0; j < 4; ++j)
                acc[i][j] = __builtin_amdgcn_mfma_f32_16x16x32_bf16(
                    aF[i], bF[j], acc[i][j], 0, 0, 0);
        __syncthreads();
    }
#pragma unroll
    for (int j = 0; j < 4; ++j) {
        const int n = n0 + wn + j * 16 + lr;
        const float s  = gamma[n] * rsqrtf(var[n] + EPSc);
        const float tv = fmaf(bias[n] - mean[n], s, beta[n]);
#pragma unroll
        for (int i = 0; i < 4; ++i) {
            const int mrow = m0 + wm + i * 16 + q * 4;
#pragma unroll
            for (int r = 0; r < 4; ++r)
                C[(size_t)(mrow + r) * N + n] = fmaf(acc[i][j][r], s, tv);
        }
    }
}

// ---------------- MFMA attention ----------------
// block = (b, h, qc); wave w -> q-tile qt=qc*4+w. LDS 46.3KB -> 3 blocks/CU.
// Layout: P 4x[16][232] (29696B) | region2: Kb[208][40] (16640B) overlaid by V[32][200] after QK.
__global__ __launch_bounds__(256)
void attn_mfma(const __bf16* __restrict__ QK, const __bf16* __restrict__ VT,
               __bf16* __restrict__ hidden)
{
    __shared__ __align__(16) char smem[46400];
    const int t = threadIdx.x;
    const int wave = t >> 6, lane = t & 63;
    const int lr = lane & 15, q = lane >> 4;
    const int bid = blockIdx.x;
    const int qc = bid & 3;
    const int bh = bid >> 2;
    const int b = bh >> 3, h = bh & 7;

    __bf16* Pw  = (__bf16*)(smem + wave * 7424);       // [16][232]
    __bf16* Kb  = (__bf16*)(smem + 29696);             // [208][40]
    char*   ldsV = smem + 29696;                       // [32][200] (overlaid on Kb)

    const __bf16* qkh = QK + (size_t)h * (25088 * 64) + (size_t)b * 196 * 64;

    // ---- stage K: rows s, elems 32..63 -> Kb[s][40] ----
    for (int fid = t; fid < 196 * 4; fid += 256) {
        int s = fid >> 2, c = fid & 3;
        bf16x8 v = *(const bf16x8*)(qkh + (size_t)s * 64 + 32 + c * 8);
        *(bf16x8*)(Kb + s * 40 + c * 8) = v;
    }
    __syncthreads();

    const int qt = qc * 4 + wave;
    const bool wactive = (qt <= 12);

    if (wactive) {
        int sQ = qt * 16 + lr; if (sQ > 195) sQ = 195;
        bf16x8 aQ = *(const bf16x8*)(qkh + (size_t)sQ * 64 + q * 8);   // Q pre-scaled

        f32x4 sc[13];
#pragma unroll
        for (int nt = 0; nt < 13; ++nt) {
            bf16x8 bK = *(const bf16x8*)(Kb + (nt * 16 + lr) * 40 + q * 8);
            f32x4 z = {0.f, 0.f, 0.f, 0.f};
            sc[nt] = __builtin_amdgcn_mfma_f32_16x16x32_bf16(aQ, bK, z, 0, 0, 0);
        }
        // ---- register softmax (cols >=196 masked; scale already folded into Q) ----
        float mrow[4] = {-1e30f, -1e30f, -1e30f, -1e30f};
#pragma unroll
        for (int nt = 0; nt < 13; ++nt) {
            const bool valid = (nt < 12) | (lr < 4);
            if (valid)
#pragma unroll
                for (int r = 0; r < 4; ++r) mrow[r] = fmaxf(mrow[r], sc[nt][r]);
        }
#pragma unroll
        for (int d = 1; d < 16; d <<= 1)
#pragma unroll
            for (int r = 0; r < 4; ++r)
                mrow[r] = fmaxf(mrow[r], __shfl_xor(mrow[r], d, 64));
        float l[4] = {0.f, 0.f, 0.f, 0.f};
#pragma unroll
        for (int nt = 0; nt < 13; ++nt) {
            const bool valid = (nt < 12) | (lr < 4);
#pragma unroll
            for (int r = 0; r < 4; ++r) {
                float e = valid ? __expf(sc[nt][r] - mrow[r]) : 0.f;
                sc[nt][r] = e;
                l[r] += e;
            }
        }
#pragma unroll
        for (int d = 1; d < 16; d <<= 1)
#pragma unroll
            for (int r = 0; r < 4; ++r)
                l[r] += __shfl_xor(l[r], d, 64);
        float inv[4];
#pragma unroll
        for (int r = 0; r < 4; ++r) inv[r] = 1.f / l[r];

        // ---- P -> LDS A-layout, packed pairs via DPP shuffle (b32 writes, conflict-free) ----
#pragma unroll
        for (int nt = 0; nt < 13; ++nt)
#pragma unroll
            for (int r = 0; r < 4; ++r) {
                __bf16 pb = (__bf16)(sc[nt][r] * inv[r]);
                unsigned short us;
                __builtin_memcpy(&us, &pb, 2);
                unsigned self = us;
                unsigned nbr  = (unsigned)__shfl_xor((int)self, 1, 64);
                if ((lr & 1) == 0) {
                    unsigned packed = self | (nbr << 16);
                    *(unsigned*)(Pw + (q * 4 + r) * 232 + nt * 16 + lr) = packed;
                }
            }
        // zero pad cols 196..231 (b32)
        for (int idx = lane; idx < 16 * 18; idx += 64) {
            int row = idx / 18, wz = idx - row * 18;
            *(unsigned*)(Pw + row * 232 + 196 + wz * 2) = 0u;
        }
    }
    __syncthreads();   // all waves done reading K -> region2 reusable for V

    const int sbase = qt * 16 + q * 4;
    const bool sval = wactive && (sbase + 3 < 196);
    __bf16* hb = hidden + (size_t)b * 200704 + (size_t)h * 25088;

    for (int q4 = 0; q4 < 4; ++q4) {
        // stage V quarter: rows h*128+q4*32+i, cols b*200..+199 -> ldsV[i][200]
#pragma unroll
        for (int rr = 0; rr < 8; ++rr) {
            const int vrow = wave * 8 + rr;
            const __bf16* gsrc = VT + (size_t)(h * 128 + q4 * 32 + vrow) * VT_NP
                               + (size_t)b * 200 + lane * 8;
            if (lane < 25)
                gl_lds16(gsrc, ldsV + vrow * 400);
        }
        __syncthreads();
        if (wactive) {
            f32x4 o0 = {0.f, 0.f, 0.f, 0.f}, o1 = {0.f, 0.f, 0.f, 0.f};
            const __bf16* Vl = (const __bf16*)ldsV;
#pragma unroll
            for (int kk = 0; kk < 7; ++kk) {
                bf16x8 aP = *(const bf16x8*)(Pw + lr * 232 + kk * 32 + q * 8);
                bf16x8 b0 = *(const bf16x8*)(Vl + lr * 200 + kk * 32 + q * 8);
                bf16x8 b1 = *(const bf16x8*)(Vl + (16 + lr) * 200 + kk * 32 + q * 8);
                o0 = __builtin_amdgcn_mfma_f32_16x16x32_bf16(aP, b0, o0, 0, 0, 0);
                o1 = __builtin_amdgcn_mfma_f32_16x16x32_bf16(aP, b1, o1, 0, 0, 0);
            }
            if (sval) {
#pragma unroll
                for (int nt2 = 0; nt2 < 2; ++nt2) {
                    f32x4 o = nt2 ? o1 : o0;
                    const int d = q4 * 32 + nt2 * 16 + lr;
                    bf16x4 pk;
#pragma unroll
                    for (int r = 0; r < 4; ++r) {
                        float x = o[r];
                        pk[r] = (__bf16)(x * fminf(fmaxf(x + 3.f, 0.f), 6.f) * (1.f / 6.f));
                    }
                    *(bf16x4*)(hb + (size_t)d * 196 + sbase) = pk;
                }
            }
        }
        if (q4 < 3) __syncthreads();
    }
}

} // namespace

extern "C" void kernel_launch(void* const* d_in, const int* in_sizes, int n_in,
                              void* d_out, int out_size, void* d_ws, size_t ws_size,
                              hipStream_t stream)
{
    const float* x    = (const float*)d_in[0];
    const float* Wqkv = (const float*)d_in[1];
    const float* bqkv = (const float*)d_in[2];
    const float* g1   = (const float*)d_in[3];
    const float* be1  = (const float*)d_in[4];
    const float* mu1  = (const float*)d_in[5];
    const float* va1  = (const float*)d_in[6];
    const float* Wp   = (const float*)d_in[7];
    const float* bp   = (const float*)d_in[8];
    const float* g2   = (const float*)d_in[9];
    const float* be2  = (const float*)d_in[10];
    const float* mu2  = (const float*)d_in[11];
    const float* va2  = (const float*)d_in[12];

    // workspace layout (bytes)
    char* ws = (char*)d_ws;
    __bf16* QKb    = (__bf16*)ws;                    // 8*25088*64*2   = 25,690,112
    __bf16* VT     = (__bf16*)(ws + 25690112);       // 1024*25600*2   = 52,428,800
    __bf16* hidden = (__bf16*)(ws + 78118912);       // 25088*1024*2   = 51,380,224
    __bf16* xb     = (__bf16*)(ws + 129499136);      // 25088*512*2    = 25,690,112
    __bf16* WTqk   = (__bf16*)(ws + 155189248);      // 512*512*2      = 524,288
    __bf16* WTv    = (__bf16*)(ws + 155713536);      // 1024*512*2     = 1,048,576
    __bf16* WT2    = (__bf16*)(ws + 156762112);      // 512*1024*2     = 1,048,576
    float*  out    = (float*)d_out;

    cvt_f32_bf16<<<dim3((Mrows * DIN / 4 + 255) / 256), dim3(256), 0, stream>>>(
        x, xb, Mrows * DIN / 4);
    transpose_cvt<<<dim3(DIN / 32, PIN / 32), dim3(256), 0, stream>>>(Wp, WT2, PIN, DIN);
    transpose_qkmap<<<dim3(16, 16), dim3(256), 0, stream>>>(Wqkv, WTqk);
    transpose_vmap<<<dim3(32, 16), dim3(256), 0, stream>>>(Wqkv, WTv);

    // QK projection + BN (+ folded softmax scale) -> QKb [h][25088][64]
    gemm_qk<<<dim3(196 * 4), dim3(256), 0, stream>>>(
        xb, WTqk, bqkv, g1, be1, mu1, va1, QKb);

    // V^T projection + BN -> VT [1024][25600]
    gemm_vt<<<dim3(8 * 200), dim3(256), 0, stream>>>(
        WTv, xb, bqkv, g1, be1, mu1, va1, VT);

    // MFMA attention -> hidden bf16 (scrambled layout)
    attn_mfma<<<dim3(Bb * Hh * 4), dim3(256), 0, stream>>>(QKb, VT, hidden);

    // GEMM2 + BN -> out fp32
    gemm_bn_mfma<DIN, PIN><<<dim3(196 * 4), dim3(256), 0, stream>>>(
        hidden, WT2, bp, g2, be2, mu2, va2, out);
}